// Round 8
// baseline (203.521 us; speedup 1.0000x reference)
//
#include <hip/hip_runtime.h>
#include <math.h>

// Problem constants (from reference setup_inputs)
constexpr int B = 64;
constexpr int T = 1024;
constexpr int C = 128;
constexpr int L = 256;
constexpr int S = 2 * L + 1;     // 513 extended states

template <int N> struct IC { static constexpr int value = N; };

// shfl_up by 1 lane as pure VALU (DPP wave_shr:1): no DS op, no lgkmcnt.
// Lane 0 gets 0 (bound_ctrl=0 -> old operand = 0), the CTC halo boundary.
__device__ __forceinline__ float shr1(float x) {
    return __int_as_float(__builtin_amdgcn_update_dpp(
        0, __float_as_int(x), 0x138 /*WAVE_SHR1*/, 0xf, 0xf, false));
}

template <int CTRL>
__device__ __forceinline__ float maxdpp(float x) {
    float t = __int_as_float(__builtin_amdgcn_update_dpp(
        __float_as_int(x), __float_as_int(x), CTRL, 0xf, 0xf, false));
    return fmaxf(x, t);
}

// Wave64 max-reduce via DPP tree, wave-uniform result (readlane 63).
__device__ __forceinline__ float wave_max_dpp(float x) {
    x = maxdpp<0x111>(x);   // row_shr:1
    x = maxdpp<0x112>(x);   // row_shr:2
    x = maxdpp<0x114>(x);   // row_shr:4
    x = maxdpp<0x118>(x);   // row_shr:8
    x = maxdpp<0x142>(x);   // row_bcast:15
    x = maxdpp<0x143>(x);   // row_bcast:31
    return __int_as_float(__builtin_amdgcn_readlane(__float_as_int(x), 63));
}

// k1: per (b,t) row — log+transpose to out_log, gather the 256 label columns
// into glab[b][t][256] (k2's lane l reads [4l..4l+3] as one float4), and
// blankcol[b][t] = row[0]. 1024 blocks x 256 thr = 16 waves/CU: the random
// gathers are TLP-hidden here instead of serializing the sequential kernel.
__global__ __launch_bounds__(256) void ctc_prep(
    const float* __restrict__ yp,      // [B,T,C]
    const int*   __restrict__ yt,      // [B,L]
    float* __restrict__ out_log,       // [T,B,C]
    float* __restrict__ glab,          // [B,T,256]
    float* __restrict__ bc)            // [B,T]
{
    const int bb   = blockIdx.x >> 4;
    const int ck   = blockIdx.x & 15;     // 64-row chunk of T
    const int wv   = threadIdx.x >> 6;    // wave 0..3 -> 16 rows each
    const int lane = threadIdx.x & 63;

    __shared__ float rowbuf[4][2][128];   // per-wave double buffer

    int4 ly = *(const int4*)(yt + bb * L + 4 * lane);
    const int tbase = ck * 64 + wv * 16;

    for (int i = 0; i < 16; ++i) {
        const int t = tbase + i;
        const float2 v = ((const float2*)(yp + ((size_t)bb * T + t) * C))[lane];
        ((float2*)rowbuf[wv][i & 1])[lane] = v;
        float2 lg; lg.x = __logf(v.x); lg.y = __logf(v.y);
        ((float2*)(out_log + ((size_t)t * B + bb) * C))[lane] = lg;
        if (lane == 0) bc[bb * T + t] = v.x;
        const float* rb = rowbuf[wv][i & 1];
        float4 g;
        g.x = rb[ly.x]; g.y = rb[ly.y]; g.z = rb[ly.z]; g.w = rb[ly.w];
        ((float4*)(glab + ((size_t)bb * T + t) * 256))[lane] = g;
    }
}

// k2: CTC forward, one 64-lane wave per batch element. Linear-prob domain,
// alpha in registers, 4-step halo-blocked wedge, DPP halos + DPP rescale.
// Label probs arrive as ONE coalesced float4/lane/row from glab via a
// 16-row register ring (4-group vmcnt slack); blanks via conflict-free
// broadcast LDS reads prefetched one group ahead. ~4 DS ops per group:
// the 4-bit-lgkmcnt drain problem of R2-R7 is structurally gone.
__global__ __launch_bounds__(64, 1) void ctc_fwd(
    const float* __restrict__ glab,    // [B,T,256]
    const float* __restrict__ bc,      // [B,T]
    const int*   __restrict__ yt,      // [B,L]
    const int*   __restrict__ il_,     // [B]
    const int*   __restrict__ ll_,     // [B]
    float* __restrict__ out_loss)      // scalar, pre-zeroed; atomic mean
{
    const int b    = blockIdx.x;
    const int lane = threadIdx.x;

    __shared__ float blanks[T];   // 4 KB
    __shared__ float afin[S];

    int il = il_[b]; il = min(max(il, 1), T);
    int ll = ll_[b]; ll = min(max(ll, 1), L);
    const float* gb_base = glab + (size_t)b * T * 256;

    // Blank column -> LDS (coalesced).
    #pragma unroll
    for (int i = 0; i < T / 64; ++i)
        blanks[i * 64 + lane] = bc[b * T + i * 64 + lane];

    // Labels for skip flags (lane owns states 8l..8l+8 in w[8..16]).
    int4 y4  = *(const int4*)(yt + b * L + 4 * lane);
    int  po  = lane ? 4 * lane - 4 : 0;
    int4 py4 = *(const int4*)(yt + b * L + po);
    int  ppw = yt[b * L + (lane >= 2 ? 4 * lane - 5 : 0)];
    int lab[8]   = {py4.x, py4.y, py4.z, py4.w, y4.x, y4.y, y4.z, y4.w};
    int labm1[8] = {ppw,   py4.x, py4.y, py4.z, py4.w, y4.x, y4.y, y4.z};
    float skf[8];
    #pragma unroll
    for (int k = 0; k < 8; ++k)
        skf[k] = ((4 * lane + k >= 5) && (lab[k] != labm1[k])) ? 1.f : 0.f;

    // 16-row register ring of own-label float4s; slot = row & 15.
    float4 rr[16];
    #pragma unroll
    for (int r = 1; r <= 16; ++r)
        rr[r & 15] = ((const float4*)(gb_base + (size_t)r * 256))[lane];

    float g00 = gb_base[0];   // p[0][label 0] (wave-uniform scalar load)

    float w[17];
    #pragma unroll
    for (int i = 0; i < 17; ++i) w[i] = 0.f;
    if (lane == 0) { w[8] = blanks[0]; w[9] = g00; }

    auto halo = [&]() {
        #pragma unroll
        for (int k = 0; k < 8; ++k) w[k] = shr1(w[8 + k]);
    };
    halo();

    float gbc[4];             // blank probs for the current group
    #pragma unroll
    for (int j = 0; j < 4; ++j) gbc[j] = blanks[1 + j];

    int lsi = 0;
    int t0 = 0;

    // One 4-step group, phase P = (t0>>2)&3 (compile-time).
    auto group = [&](auto Pc) {
        constexpr int P = decltype(Pc)::value;
        float4 gj[4] = { rr[(4 * P + 1) & 15], rr[(4 * P + 2) & 15],
                         rr[(4 * P + 3) & 15], rr[(4 * P + 4) & 15] };
        float g1[4], g2[4], g3[4];
        #pragma unroll
        for (int j = 0; j < 4; ++j) {
            g1[j] = shr1(gj[j].y);
            g2[j] = shr1(gj[j].z);
            g3[j] = shr1(gj[j].w);
        }
        // wedge: 4 halo-blocked steps, in-place descending.
        #pragma unroll
        for (int j = 0; j < 4; ++j) {
            #pragma unroll
            for (int i = 16; i >= 2 * (j + 1); --i) {
                float acc = w[i] + w[i - 1];
                float g;
                if (i & 1) {
                    const int k = (i - 1) >> 1;
                    acc = fmaf(skf[k], w[i - 2], acc);
                    g = (k == 4) ? gj[j].x : (k == 5) ? gj[j].y :
                        (k == 6) ? gj[j].z : (k == 7) ? gj[j].w :
                        (k == 1) ? g1[j]   : (k == 2) ? g2[j] : g3[j];
                } else {
                    g = gbc[j];
                }
                w[i] = acc * g;
            }
        }
        // refill ring with rows t0+17..20 (consumed 4 groups from now).
        #pragma unroll
        for (int j = 0; j < 4; ++j) {
            int r = t0 + 17 + j; r = r > T - 1 ? T - 1 : r;
            rr[(4 * P + 1 + j) & 15] =
                ((const float4*)(gb_base + (size_t)r * 256))[lane];
        }
        // blanks for the next group (one group of LDS slack).
        #pragma unroll
        for (int j = 0; j < 4; ++j) {
            int r = t0 + 5 + j; r = r > T - 1 ? T - 1 : r;
            gbc[j] = blanks[r];
        }
        halo();
        t0 += 4;
    };

    auto maxw = [&]() {
        return fmaxf(fmaxf(fmaxf(w[8], w[9]), fmaxf(w[10], w[11])),
                     fmaxf(fmaxf(w[12], w[13]),
                           fmaxf(fmaxf(w[14], w[15]), w[16])));
    };
    auto rescale = [&]() {   // exact pow-2 rescale, centered at 2^96
        float mm = wave_max_dpp(maxw());
        int eb = (__float_as_int(mm) >> 23) & 0xff;
        int sh = 350 - eb;
        sh = sh > 254 ? 254 : (sh < 1 ? 1 : sh);
        float inv = __int_as_float(sh << 23);
        #pragma unroll
        for (int i = 8; i < 17; ++i) w[i] *= inv;
        lsi -= sh - 127;
    };

    const int full_end = ((il - 1) >> 2) << 2;

    while (t0 + 16 <= full_end) {
        group(IC<0>{});
        group(IC<1>{});
        rescale();
        group(IC<2>{});
        group(IC<3>{});
        rescale();
    }
    if (t0 + 4 <= full_end) { group(IC<0>{}); rescale(); }
    if (t0 + 4 <= full_end) { group(IC<1>{}); rescale(); }
    if (t0 + 4 <= full_end) { group(IC<2>{}); }

    // Tail: rows full_end+1 .. il-1 (0..3 steps); ring holds them.
    const int ph = (full_end >> 2) & 3;
    float4 tg[3];
    switch (ph) {
    case 0:  tg[0]=rr[1];  tg[1]=rr[2];  tg[2]=rr[3];  break;
    case 1:  tg[0]=rr[5];  tg[1]=rr[6];  tg[2]=rr[7];  break;
    case 2:  tg[0]=rr[9];  tg[1]=rr[10]; tg[2]=rr[11]; break;
    default: tg[0]=rr[13]; tg[1]=rr[14]; tg[2]=rr[15]; break;
    }
    #pragma unroll
    for (int j = 0; j < 3; ++j) {
        int r = full_end + 1 + j;
        if (r < il) {   // wave-uniform
            float hh = shr1(w[15]);
            float gb = blanks[r];
            float n8  = (w[8] + hh) * gb;
            float n9  = fmaf(skf[4], hh,    w[9]  + w[8])  * tg[j].x;
            float n10 = (w[10] + w[9])  * gb;
            float n11 = fmaf(skf[5], w[9],  w[11] + w[10]) * tg[j].y;
            float n12 = (w[12] + w[11]) * gb;
            float n13 = fmaf(skf[6], w[11], w[13] + w[12]) * tg[j].z;
            float n14 = (w[14] + w[13]) * gb;
            float n15 = fmaf(skf[7], w[13], w[15] + w[14]) * tg[j].w;
            float n16 = (w[16] + w[15]) * gb;
            w[8] = n8;  w[9] = n9;  w[10] = n10; w[11] = n11; w[12] = n12;
            w[13] = n13; w[14] = n14; w[15] = n15; w[16] = n16;
        }
    }

    // Loss: -ln(alpha[2ll-1] + alpha[2ll]) with accumulated scale.
    #pragma unroll
    for (int k = 0; k < 8; ++k) afin[8 * lane + k] = w[8 + k];
    if (lane == 63) afin[512] = w[16];
    __syncthreads();
    if (lane == 0) {
        float e1 = afin[2 * ll - 1];
        float e2 = afin[2 * ll];
        float sum = fmaxf(e1 + e2, 1e-37f);
        float loss = -(__log2f(sum) + (float)lsi) * 0.6931471805599453f;
        atomicAdd(out_loss, loss * (1.0f / (float)B));
    }
}

extern "C" void kernel_launch(void* const* d_in, const int* in_sizes, int n_in,
                              void* d_out, int out_size, void* d_ws, size_t ws_size,
                              hipStream_t stream) {
    const int*   y_true = (const int*)d_in[0];
    const float* y_pred = (const float*)d_in[1];
    const int*   in_len = (const int*)d_in[2];
    const int*   lb_len = (const int*)d_in[3];

    float* out_log  = (float*)d_out;                      // [T,B,C]
    float* out_loss = (float*)d_out + (size_t)T * B * C;  // scalar

    float* glab = (float*)d_ws;                           // [B,T,256] = 64 MB
    float* bcol = glab + (size_t)B * T * 256;             // [B,T]

    hipMemsetAsync(out_loss, 0, sizeof(float), stream);
    ctc_prep<<<B * 16, 256, 0, stream>>>(y_pred, y_true, out_log, glab, bcol);
    ctc_fwd<<<B, 64, 0, stream>>>(glab, bcol, y_true, in_len, lb_len, out_loss);
}